// Round 4
// baseline (377.422 us; speedup 1.0000x reference)
//
#include <hip/hip_runtime.h>

#define B 2
#define E 1024
#define T 2048
#define H 16
#define DH 64

// log2(e) / sqrt(E)
#define SCALE2 0.0450842200277801f

typedef __bf16 bf16x8 __attribute__((ext_vector_type(8)));
typedef float f32x4 __attribute__((ext_vector_type(4)));
typedef float f32x16 __attribute__((ext_vector_type(16)));
typedef unsigned short ushort8v __attribute__((ext_vector_type(8)));

__device__ __forceinline__ f32x4 mfma16(bf16x8 a, bf16x8 b, f32x4 c) {
  return __builtin_amdgcn_mfma_f32_16x16x32_bf16(a, b, c, 0, 0, 0);
}
__device__ __forceinline__ f32x16 mfma32(bf16x8 a, bf16x8 b, f32x16 c) {
  return __builtin_amdgcn_mfma_f32_32x32x16_bf16(a, b, c, 0, 0, 0);
}
__device__ __forceinline__ unsigned short bf16u(float x) {
  __bf16 h = (__bf16)x;
  return __builtin_bit_cast(unsigned short, h);
}
__device__ __forceinline__ void split_bf(float x, unsigned short& h, unsigned short& l) {
  __bf16 hb = (__bf16)x;
  float rem = x - (float)hb;
  h = __builtin_bit_cast(unsigned short, hb);
  l = bf16u(rem);
}

// ---------------------------------------------------------------------------
// Weight prep: Wq/Wk/Wv -> single bf16; Wo -> hi/lo bf16 split.
// ---------------------------------------------------------------------------
__global__ __launch_bounds__(256) void prep_weights(
    const float* __restrict__ Wq, const float* __restrict__ Wk,
    const float* __restrict__ Wv, const float* __restrict__ Wo,
    unsigned short* __restrict__ WqB, unsigned short* __restrict__ WkB,
    unsigned short* __restrict__ WvB, unsigned short* __restrict__ WoHi,
    unsigned short* __restrict__ WoLo) {
  const int which = blockIdx.y;
  const int i = (blockIdx.x * 256 + threadIdx.x) * 4;
  const float* src = which == 0 ? Wq : which == 1 ? Wk : which == 2 ? Wv : Wo;
  float4 v = *(const float4*)&src[i];
  if (which < 3) {
    unsigned short* dst = which == 0 ? WqB : which == 1 ? WkB : WvB;
    ((unsigned int*)&dst[i])[0] = bf16u(v.x) | ((unsigned)bf16u(v.y) << 16);
    ((unsigned int*)&dst[i])[1] = bf16u(v.z) | ((unsigned)bf16u(v.w) << 16);
  } else {
    unsigned short h[4], l[4];
    float vv[4] = {v.x, v.y, v.z, v.w};
#pragma unroll
    for (int j = 0; j < 4; ++j) split_bf(vv[j], h[j], l[j]);
    ((unsigned int*)&WoHi[i])[0] = h[0] | ((unsigned)h[1] << 16);
    ((unsigned int*)&WoHi[i])[1] = h[2] | ((unsigned)h[3] << 16);
    ((unsigned int*)&WoLo[i])[0] = l[0] | ((unsigned)l[1] << 16);
    ((unsigned int*)&WoLo[i])[1] = l[2] | ((unsigned)l[3] << 16);
  }
}

// ---------------------------------------------------------------------------
// Transpose + convert: X [B][E][T] fp32 -> Xt [B][T][E] bf16 (q,k,v in one)
// ---------------------------------------------------------------------------
__global__ __launch_bounds__(256) void transpose_cvt(
    const float* __restrict__ q, const float* __restrict__ k,
    const float* __restrict__ v, unsigned short* __restrict__ XtQ,
    unsigned short* __restrict__ XtK, unsigned short* __restrict__ XtV) {
  __shared__ float Xs[32 * 36];
  const int z = blockIdx.z, which = z >> 1, b = z & 1;
  const float* X = which == 0 ? q : which == 1 ? k : v;
  unsigned short* O = which == 0 ? XtQ : which == 1 ? XtK : XtV;
  const int e0 = blockIdx.y * 32, t0 = blockIdx.x * 32;
  const int tid = threadIdx.x;
  const int r = tid >> 3, c = (tid & 7) * 4;
  *(float4*)&Xs[r * 36 + c] = *(const float4*)&X[((size_t)b * E + e0 + r) * T + t0 + c];
  __syncthreads();
  unsigned short h[4];
#pragma unroll
  for (int j = 0; j < 4; ++j) h[j] = bf16u(Xs[(c + j) * 36 + r]);
  const size_t o = ((size_t)b * T + t0 + r) * E + e0 + c;
  ((unsigned int*)&O[o])[0] = h[0] | ((unsigned)h[1] << 16);
  ((unsigned int*)&O[o])[1] = h[2] | ((unsigned)h[3] << 16);
}

// ---------------------------------------------------------------------------
// Fused q/k/v projection, single bf16.
// which 0: Q_eff = qmask*SCALE2*(W x + b)  (t-major [B][T][E])
// which 1: K_eff = kmask*(W x + b)         (t-major [B][T][E])
// which 2: vp    = vmask*(W x) + b         (d-major [B][E][T])
// masks are exactly {0,1} so mask^2 == mask.
// ---------------------------------------------------------------------------
__global__ __launch_bounds__(256) void proj_qkv(
    const unsigned short* __restrict__ WqB, const unsigned short* __restrict__ WkB,
    const unsigned short* __restrict__ WvB, const unsigned short* __restrict__ XtQ,
    const unsigned short* __restrict__ XtK, const unsigned short* __restrict__ XtV,
    const float* __restrict__ bq, const float* __restrict__ bk,
    const float* __restrict__ bv, const float* __restrict__ qmask,
    const float* __restrict__ kmask, const float* __restrict__ vmask,
    unsigned short* __restrict__ qpT, unsigned short* __restrict__ kpT,
    unsigned short* __restrict__ vp) {
  __shared__ unsigned short Ah[128 * 72], Bs[128 * 72];
  const int b = blockIdx.z, my = blockIdx.y;
  const int which = my >> 3, o0 = (my & 7) * 128, t0 = blockIdx.x * 128;
  const unsigned short* W = which == 0 ? WqB : which == 1 ? WkB : WvB;
  const unsigned short* Xt = which == 0 ? XtQ : which == 1 ? XtK : XtV;
  const float* bias = which == 0 ? bq : which == 1 ? bk : bv;
  const float* mask = which == 0 ? qmask : which == 1 ? kmask : vmask;

  const int tid = threadIdx.x, wave = tid >> 6, lane = tid & 63;
  const int lg = lane & 15, quad = lane >> 4;
  const int wm = (wave & 1) * 64, wn = (wave >> 1) * 64;
  const int sr = tid >> 3, sc = (tid & 7) * 8;

  f32x4 acc[4][4];
#pragma unroll
  for (int i = 0; i < 4; ++i)
#pragma unroll
    for (int j = 0; j < 4; ++j) acc[i][j] = (f32x4){0.f, 0.f, 0.f, 0.f};

  for (int k0 = 0; k0 < E; k0 += 64) {
    ushort8v ra[4], rb[4];
#pragma unroll
    for (int p = 0; p < 4; ++p) {
      ra[p] = *(const ushort8v*)&W[(size_t)(o0 + p * 32 + sr) * E + k0 + sc];
      rb[p] = *(const ushort8v*)&Xt[((size_t)b * T + t0 + p * 32 + sr) * E + k0 + sc];
    }
    __syncthreads();
#pragma unroll
    for (int p = 0; p < 4; ++p) {
      *(ushort8v*)&Ah[(p * 32 + sr) * 72 + sc] = ra[p];
      *(ushort8v*)&Bs[(p * 32 + sr) * 72 + sc] = rb[p];
    }
    __syncthreads();
    bf16x8 af[4][2];
#pragma unroll
    for (int mt = 0; mt < 4; ++mt) {
      af[mt][0] = *(const bf16x8*)&Ah[(wm + mt * 16 + lg) * 72 + quad * 8];
      af[mt][1] = *(const bf16x8*)&Ah[(wm + mt * 16 + lg) * 72 + 32 + quad * 8];
    }
#pragma unroll
    for (int nt = 0; nt < 4; ++nt) {
      bf16x8 b0 = *(const bf16x8*)&Bs[(wn + nt * 16 + lg) * 72 + quad * 8];
      bf16x8 b1 = *(const bf16x8*)&Bs[(wn + nt * 16 + lg) * 72 + 32 + quad * 8];
#pragma unroll
      for (int mt = 0; mt < 4; ++mt) {
        f32x4 c = acc[mt][nt];
        c = mfma16(af[mt][0], b0, c);
        c = mfma16(af[mt][1], b1, c);
        acc[mt][nt] = c;
      }
    }
  }
#pragma unroll
  for (int nt = 0; nt < 4; ++nt) {
    const int tcol = t0 + wn + nt * 16 + lg;
    const float mv = mask[b * T + tcol];
#pragma unroll
    for (int mt = 0; mt < 4; ++mt) {
      const int oF = o0 + wm + mt * 16 + quad * 4;
      float v4[4];
      if (which == 0) {
        const float s = mv * SCALE2;
#pragma unroll
        for (int r = 0; r < 4; ++r) v4[r] = (acc[mt][nt][r] + bias[oF + r]) * s;
      } else if (which == 1) {
#pragma unroll
        for (int r = 0; r < 4; ++r) v4[r] = (acc[mt][nt][r] + bias[oF + r]) * mv;
      } else {
#pragma unroll
        for (int r = 0; r < 4; ++r) v4[r] = acc[mt][nt][r] * mv + bias[oF + r];
      }
      if (which <= 1) {
        unsigned short* O = which == 0 ? qpT : kpT;
        const size_t o = ((size_t)b * T + tcol) * E + oF;
        ((unsigned int*)&O[o])[0] = bf16u(v4[0]) | ((unsigned)bf16u(v4[1]) << 16);
        ((unsigned int*)&O[o])[1] = bf16u(v4[2]) | ((unsigned)bf16u(v4[3]) << 16);
      } else {
#pragma unroll
        for (int r = 0; r < 4; ++r)
          vp[((size_t)b * E + oF + r) * T + tcol] = bf16u(v4[r]);
      }
    }
  }
}

// ---------------------------------------------------------------------------
// Stats: lInv[q] = 1 / sum_k exp2(S_eff[q,k]). LDS-free, barrier-free.
// 32x32x16 MFMA; Q-frags resident per wave (32 q-rows), K-frags direct-global
// with 1-deep prefetch. Grid (T/128, B*H), 256 thr.
// C-layout: col=lane&31, row=(reg&3)+8*(reg>>2)+4*(lane>>5).
// ---------------------------------------------------------------------------
__global__ __launch_bounds__(256) void attn_stats(
    const unsigned short* __restrict__ qpT, const unsigned short* __restrict__ kpT,
    float* __restrict__ lInvOut) {
  const int bh = blockIdx.y, b = bh >> 4, h = bh & 15;
  const int q0 = blockIdx.x * 128;
  const int tid = threadIdx.x, wave = tid >> 6, lane = tid & 63;
  const int ln = lane & 31, half = lane >> 5;

  const bf16x8* qrow =
      (const bf16x8*)(qpT + ((size_t)b * T + q0 + wave * 32 + ln) * E + h * DH);
  bf16x8 aq[4];
#pragma unroll
  for (int s = 0; s < 4; ++s) aq[s] = qrow[s * 2 + half];

  float lacc[16];
#pragma unroll
  for (int r = 0; r < 16; ++r) lacc[r] = 0.f;

  bf16x8 bk[2][4];
#pragma unroll
  for (int nt = 0; nt < 2; ++nt) {
    const bf16x8* kr = (const bf16x8*)(kpT + ((size_t)b * T + nt * 32 + ln) * E + h * DH);
#pragma unroll
    for (int s = 0; s < 4; ++s) bk[nt][s] = kr[s * 2 + half];
  }
  for (int kt = 0; kt < T; kt += 64) {
    const int kn = (kt + 64) & (T - 1);
    bf16x8 nb[2][4];
#pragma unroll
    for (int nt = 0; nt < 2; ++nt) {
      const bf16x8* kr =
          (const bf16x8*)(kpT + ((size_t)b * T + kn + nt * 32 + ln) * E + h * DH);
#pragma unroll
      for (int s = 0; s < 4; ++s) nb[nt][s] = kr[s * 2 + half];
    }
    f32x16 S0 = {}, S1 = {};
#pragma unroll
    for (int s = 0; s < 4; ++s) {
      S0 = mfma32(aq[s], bk[0][s], S0);
      S1 = mfma32(aq[s], bk[1][s], S1);
    }
#pragma unroll
    for (int r = 0; r < 16; ++r) lacc[r] += exp2f(S0[r]) + exp2f(S1[r]);
#pragma unroll
    for (int nt = 0; nt < 2; ++nt)
#pragma unroll
      for (int s = 0; s < 4; ++s) bk[nt][s] = nb[nt][s];
  }
  // reduce across the 32 column-lanes (xor < 32 keeps `half` fixed)
#pragma unroll
  for (int off = 1; off < 32; off <<= 1)
#pragma unroll
    for (int r = 0; r < 16; ++r) lacc[r] += __shfl_xor(lacc[r], off, 64);
  if (ln == 0) {
#pragma unroll
    for (int t = 0; t < 4; ++t) {
      f32x4 o;
#pragma unroll
      for (int j = 0; j < 4; ++j) o[j] = 1.0f / lacc[t * 4 + j];
      *(f32x4*)&lInvOut[(size_t)bh * T + q0 + wave * 32 + t * 8 + half * 4] = o;
    }
  }
}

// ---------------------------------------------------------------------------
// Apply: ao[d,k] = sum_q (V[d,q]*lInv[q]) * exp2(S_eff[q,k]).
// 32x32x16; wave owns 32 k-cols (block 128). K/Q frags direct-global;
// V staged in double-buffered LDS with lInv premultiplied (1 barrier/iter);
// P transpose region is wave-private (no barrier). Output hi/lo bf16 t-major.
// ---------------------------------------------------------------------------
__global__ __launch_bounds__(256) void attn_apply(
    const unsigned short* __restrict__ qpT, const unsigned short* __restrict__ kpT,
    const unsigned short* __restrict__ vp, const float* __restrict__ lInv,
    unsigned short* __restrict__ aoHi, unsigned short* __restrict__ aoLo) {
  __shared__ unsigned short Vs[2][64 * 68];
  __shared__ unsigned short Pt[128 * 68];
  const int bh = blockIdx.y, b = bh >> 4, h = bh & 15;
  const int kblk = blockIdx.x * 128;
  const int tid = threadIdx.x, wave = tid >> 6, lane = tid & 63;
  const int ln = lane & 31, half = lane >> 5;

  // resident K_eff B-frags for this wave's 32 k-cols
  const bf16x8* krow =
      (const bf16x8*)(kpT + ((size_t)b * T + kblk + wave * 32 + ln) * E + h * DH);
  bf16x8 bkk[4];
#pragma unroll
  for (int s = 0; s < 4; ++s) bkk[s] = krow[s * 2 + half];

  f32x16 acc0 = {}, acc1 = {};

  // staging: thread -> V row d = tid>>2, 16 cols at (tid&3)*16
  const int sd = tid >> 2, sc = (tid & 3) * 16;
  const unsigned short* vrow = vp + ((size_t)b * E + h * DH + sd) * T + sc;
  const float* lrow = lInv + (size_t)bh * T + sc;

  ushort8v v0 = *(const ushort8v*)(vrow);
  ushort8v v1 = *(const ushort8v*)(vrow + 8);
  f32x4 li[4];
#pragma unroll
  for (int j = 0; j < 4; ++j) li[j] = *(const f32x4*)(lrow + j * 4);

  for (int qt = 0; qt < T; qt += 64) {
    const int cur = (qt >> 6) & 1;
    // Q-frag loads for this iter (consumed after the barrier)
    bf16x8 aq[2][4];
#pragma unroll
    for (int mt = 0; mt < 2; ++mt) {
      const bf16x8* qr =
          (const bf16x8*)(qpT + ((size_t)b * T + qt + mt * 32 + ln) * E + h * DH);
#pragma unroll
      for (int s = 0; s < 4; ++s) aq[mt][s] = qr[s * 2 + half];
    }
    // premultiply lInv into V, write Vs[cur]
    {
      unsigned short px[16];
      const unsigned short* vv0 = (const unsigned short*)&v0;
      const unsigned short* vv1 = (const unsigned short*)&v1;
#pragma unroll
      for (int j = 0; j < 16; ++j) {
        unsigned int u = (unsigned int)(j < 8 ? vv0[j] : vv1[j - 8]) << 16;
        float f = __builtin_bit_cast(float, u) * li[j >> 2][j & 3];
        px[j] = bf16u(f);
      }
      *(ushort8v*)&Vs[cur][sd * 68 + sc] = *(ushort8v*)&px[0];
      *(ushort8v*)&Vs[cur][sd * 68 + sc + 8] = *(ushort8v*)&px[8];
    }
    // prefetch next iter's V/lInv (wraps harmlessly on last iter)
    const int qn = (qt + 64) & (T - 1);
    v0 = *(const ushort8v*)(vrow + qn);
    v1 = *(const ushort8v*)(vrow + qn + 8);
#pragma unroll
    for (int j = 0; j < 4; ++j) li[j] = *(const f32x4*)(lrow + qn + j * 4);
    __syncthreads();
    // S -> P -> Pt (wave-private rows: own k-cols)
#pragma unroll
    for (int mt = 0; mt < 2; ++mt) {
      f32x16 S = {};
#pragma unroll
      for (int s = 0; s < 4; ++s) S = mfma32(aq[mt][s], bkk[s], S);
#pragma unroll
      for (int t = 0; t < 4; ++t) {
        unsigned short p0 = bf16u(exp2f(S[t * 4 + 0]));
        unsigned short p1 = bf16u(exp2f(S[t * 4 + 1]));
        unsigned short p2 = bf16u(exp2f(S[t * 4 + 2]));
        unsigned short p3 = bf16u(exp2f(S[t * 4 + 3]));
        uint2 w;
        w.x = p0 | ((unsigned)p1 << 16);
        w.y = p2 | ((unsigned)p3 << 16);
        *(uint2*)&Pt[(wave * 32 + ln) * 68 + mt * 32 + t * 8 + half * 4] = w;
      }
    }
    // PV: A = V*lInv (LDS), B = P (wave-private LDS, same-wave DS order)
#pragma unroll
    for (int s = 0; s < 4; ++s) {
      bf16x8 pb = *(const bf16x8*)&Pt[(wave * 32 + ln) * 68 + s * 16 + half * 8];
      bf16x8 av0 = *(const bf16x8*)&Vs[cur][ln * 68 + s * 16 + half * 8];
      bf16x8 av1 = *(const bf16x8*)&Vs[cur][(32 + ln) * 68 + s * 16 + half * 8];
      acc0 = mfma32(av0, pb, acc0);
      acc1 = mfma32(av1, pb, acc1);
    }
  }
  // epilogue: hi/lo split, t-major [B][T][E]
  const int kcol = kblk + wave * 32 + ln;
  const size_t obase = ((size_t)b * T + kcol) * E + h * DH;
#pragma unroll
  for (int mt = 0; mt < 2; ++mt) {
#pragma unroll
    for (int t = 0; t < 4; ++t) {
      unsigned short hh[4], ll[4];
#pragma unroll
      for (int j = 0; j < 4; ++j) {
        float x = mt ? acc1[t * 4 + j] : acc0[t * 4 + j];
        split_bf(x, hh[j], ll[j]);
      }
      const size_t o = obase + mt * 32 + t * 8 + half * 4;
      uint2 wH, wL;
      wH.x = hh[0] | ((unsigned)hh[1] << 16);
      wH.y = hh[2] | ((unsigned)hh[3] << 16);
      wL.x = ll[0] | ((unsigned)ll[1] << 16);
      wL.y = ll[2] | ((unsigned)ll[3] << 16);
      *(uint2*)&aoHi[o] = wH;
      *(uint2*)&aoLo[o] = wL;
    }
  }
}

// ---------------------------------------------------------------------------
// Final projection, hi/lo split (3 mfma): out = km[t]*(Wo . ao) + bo, fp32.
// ---------------------------------------------------------------------------
__global__ __launch_bounds__(256) void proj_final(
    const unsigned short* __restrict__ WoHi, const unsigned short* __restrict__ WoLo,
    const unsigned short* __restrict__ aoHi, const unsigned short* __restrict__ aoLo,
    const float* __restrict__ bo, const float* __restrict__ kmask,
    float* __restrict__ out) {
  __shared__ unsigned short Ah[128 * 40], Al[128 * 40], Bh[128 * 40], Bl[128 * 40];
  const int b = blockIdx.z, o0 = blockIdx.y * 128, t0 = blockIdx.x * 128;
  const int tid = threadIdx.x, wave = tid >> 6, lane = tid & 63;
  const int lg = lane & 15, quad = lane >> 4;
  const int wm = (wave & 1) * 64, wn = (wave >> 1) * 64;
  const int sr = tid >> 1, sc = (tid & 1) * 16;

  f32x4 acc[4][4];
#pragma unroll
  for (int i = 0; i < 4; ++i)
#pragma unroll
    for (int j = 0; j < 4; ++j) acc[i][j] = (f32x4){0.f, 0.f, 0.f, 0.f};

  for (int k0 = 0; k0 < E; k0 += 32) {
    const size_t ga = (size_t)(o0 + sr) * E + k0 + sc;
    const size_t gb = ((size_t)b * T + t0 + sr) * E + k0 + sc;
    ushort8v a0 = *(const ushort8v*)&WoHi[ga];
    ushort8v a1 = *(const ushort8v*)&WoHi[ga + 8];
    ushort8v a2 = *(const ushort8v*)&WoLo[ga];
    ushort8v a3 = *(const ushort8v*)&WoLo[ga + 8];
    ushort8v b0 = *(const ushort8v*)&aoHi[gb];
    ushort8v b1 = *(const ushort8v*)&aoHi[gb + 8];
    ushort8v b2 = *(const ushort8v*)&aoLo[gb];
    ushort8v b3 = *(const ushort8v*)&aoLo[gb + 8];
    __syncthreads();
    *(ushort8v*)&Ah[sr * 40 + sc] = a0;
    *(ushort8v*)&Ah[sr * 40 + sc + 8] = a1;
    *(ushort8v*)&Al[sr * 40 + sc] = a2;
    *(ushort8v*)&Al[sr * 40 + sc + 8] = a3;
    *(ushort8v*)&Bh[sr * 40 + sc] = b0;
    *(ushort8v*)&Bh[sr * 40 + sc + 8] = b1;
    *(ushort8v*)&Bl[sr * 40 + sc] = b2;
    *(ushort8v*)&Bl[sr * 40 + sc + 8] = b3;
    __syncthreads();
    bf16x8 afh[4], afl[4];
#pragma unroll
    for (int mt = 0; mt < 4; ++mt) {
      afh[mt] = *(const bf16x8*)&Ah[(wm + mt * 16 + lg) * 40 + quad * 8];
      afl[mt] = *(const bf16x8*)&Al[(wm + mt * 16 + lg) * 40 + quad * 8];
    }
#pragma unroll
    for (int nt = 0; nt < 4; ++nt) {
      bf16x8 bh_ = *(const bf16x8*)&Bh[(wn + nt * 16 + lg) * 40 + quad * 8];
      bf16x8 bl_ = *(const bf16x8*)&Bl[(wn + nt * 16 + lg) * 40 + quad * 8];
#pragma unroll
      for (int mt = 0; mt < 4; ++mt) {
        f32x4 c = acc[mt][nt];
        c = mfma16(afh[mt], bh_, c);
        c = mfma16(afh[mt], bl_, c);
        c = mfma16(afl[mt], bh_, c);
        acc[mt][nt] = c;
      }
    }
  }
#pragma unroll
  for (int nt = 0; nt < 4; ++nt) {
    const int tcol = t0 + wn + nt * 16 + lg;
    const float mv = kmask[b * T + tcol];
#pragma unroll
    for (int mt = 0; mt < 4; ++mt) {
      const int oF = o0 + wm + mt * 16 + quad * 4;
#pragma unroll
      for (int r = 0; r < 4; ++r)
        out[((size_t)b * E + oF + r) * T + tcol] = acc[mt][nt][r] * mv + bo[oF + r];
    }
  }
}

extern "C" void kernel_launch(void* const* d_in, const int* in_sizes, int n_in,
                              void* d_out, int out_size, void* d_ws, size_t ws_size,
                              hipStream_t stream) {
  const float* q = (const float*)d_in[0];
  const float* k = (const float*)d_in[1];
  const float* v = (const float*)d_in[2];
  const float* qmask = (const float*)d_in[3];
  const float* kmask = (const float*)d_in[4];
  const float* vmask = (const float*)d_in[5];
  const float* Wq = (const float*)d_in[6];
  const float* bq = (const float*)d_in[7];
  const float* Wk = (const float*)d_in[8];
  const float* bk = (const float*)d_in[9];
  const float* Wv = (const float*)d_in[10];
  const float* bv = (const float*)d_in[11];
  const float* Wo = (const float*)d_in[12];
  const float* bo = (const float*)d_in[13];

  char* w = (char*)d_ws;
  const size_t WB = (size_t)E * E * sizeof(unsigned short);      // 2 MB
  const size_t TB = (size_t)B * T * E * sizeof(unsigned short);  // 8 MB
  unsigned short* WqB = (unsigned short*)(w + 0 * WB);
  unsigned short* WkB = (unsigned short*)(w + 1 * WB);
  unsigned short* WvB = (unsigned short*)(w + 2 * WB);
  unsigned short* WoHi = (unsigned short*)(w + 3 * WB);
  unsigned short* WoLo = (unsigned short*)(w + 4 * WB);
  size_t off = 5 * WB;
  unsigned short* XtQ = (unsigned short*)(w + off); off += TB;
  unsigned short* XtK = (unsigned short*)(w + off); off += TB;
  unsigned short* XtV = (unsigned short*)(w + off); off += TB;
  unsigned short* qpT = (unsigned short*)(w + off); off += TB;
  unsigned short* kpT = (unsigned short*)(w + off); off += TB;
  unsigned short* vp  = (unsigned short*)(w + off); off += TB;
  float* lInv = (float*)(w + off); off += (size_t)B * H * T * sizeof(float);
  // attention output aliases XtQ/XtK (dead after proj_qkv)
  unsigned short* aoHi = XtQ;
  unsigned short* aoLo = XtK;

  dim3 bl(256);
  prep_weights<<<dim3((E * E) / 1024, 4), bl, 0, stream>>>(
      Wq, Wk, Wv, Wo, WqB, WkB, WvB, WoHi, WoLo);
  transpose_cvt<<<dim3(T / 32, E / 32, 3 * B), bl, 0, stream>>>(
      q, k, v, XtQ, XtK, XtV);
  proj_qkv<<<dim3(T / 128, 24, B), bl, 0, stream>>>(
      WqB, WkB, WvB, XtQ, XtK, XtV, bq, bk, bv, qmask, kmask, vmask, qpT, kpT, vp);
  attn_stats<<<dim3(T / 128, B * H), bl, 0, stream>>>(qpT, kpT, lInv);
  attn_apply<<<dim3(T / 128, B * H), bl, 0, stream>>>(
      qpT, kpT, vp, lInv, aoHi, aoLo);
  proj_final<<<dim3(T / 128, E / 128, B), bl, 0, stream>>>(
      WoHi, WoLo, aoHi, aoLo, bo, kmask, (float*)d_out);
}